// Round 1
// baseline (4522.862 us; speedup 1.0000x reference)
//
#include <hip/hip_runtime.h>

#define N_NODES 100000
#define N_EDGES 1600000
#define IN_DIM  128
#define HID_DIM 32
#define OUT_DIM 32

// ---------------- degree / norm ----------------

__global__ void init_deg_kernel(float* deg, int n) {
    int i = blockIdx.x * blockDim.x + threadIdx.x;
    if (i < n) deg[i] = 1.0f;   // self-loop weight
}

__global__ void deg_edges_kernel(const int* __restrict__ ei, const float* __restrict__ ea,
                                 float* __restrict__ deg) {
    int e = blockIdx.x * blockDim.x + threadIdx.x;
    if (e < N_EDGES) {
        int col = ei[N_EDGES + e];
        atomicAdd(&deg[col], ea[e]);
    }
}

__global__ void make_dinv_kernel(float* deg, int n) {
    int i = blockIdx.x * blockDim.x + threadIdx.x;
    if (i < n) {
        float d = deg[i];
        deg[i] = (d > 0.0f) ? rsqrtf(d) : 0.0f;
    }
}

// ---------------- matmul: x[N,128] @ W[128,32] -> h[N,32] ----------------
// 8 threads per node; thread t computes outputs {t, t+8, t+16, t+24}.

__global__ void matmul_in_kernel(const float* __restrict__ x, const float* __restrict__ W,
                                 float* __restrict__ h) {
    __shared__ float Ws[IN_DIM * HID_DIM];   // 16 KB
    for (int i = threadIdx.x; i < IN_DIM * HID_DIM; i += blockDim.x) Ws[i] = W[i];
    __syncthreads();
    int gid = blockIdx.x * blockDim.x + threadIdx.x;
    int v = gid >> 3;
    int t = gid & 7;
    if (v >= N_NODES) return;
    const float* xr = x + (size_t)v * IN_DIM;
    float a0 = 0.f, a1 = 0.f, a2 = 0.f, a3 = 0.f;
#pragma unroll
    for (int j = 0; j < IN_DIM; j += 4) {
        float4 xv = *(const float4*)(xr + j);
        const float* w = &Ws[j * HID_DIM + t];
        a0 += xv.x * w[0];   a1 += xv.x * w[8];   a2 += xv.x * w[16];  a3 += xv.x * w[24];
        a0 += xv.y * w[32];  a1 += xv.y * w[40];  a2 += xv.y * w[48];  a3 += xv.y * w[56];
        a0 += xv.z * w[64];  a1 += xv.z * w[72];  a2 += xv.z * w[80];  a3 += xv.z * w[88];
        a0 += xv.w * w[96];  a1 += xv.w * w[104]; a2 += xv.w * w[112]; a3 += xv.w * w[120];
    }
    float* hr = h + (size_t)v * HID_DIM;
    hr[t] = a0; hr[t + 8] = a1; hr[t + 16] = a2; hr[t + 24] = a3;
}

// ---------------- matmul: hmix[N,32] @ Wo[32,32] -> h2[N,32], plus self-loop into out ----

__global__ void matmul_hid_kernel(const float* __restrict__ hin, const float* __restrict__ Wo,
                                  const float* __restrict__ dinv,
                                  float* __restrict__ h2, float* __restrict__ out) {
    __shared__ float Ws[HID_DIM * OUT_DIM];  // 4 KB
    for (int i = threadIdx.x; i < HID_DIM * OUT_DIM; i += blockDim.x) Ws[i] = Wo[i];
    __syncthreads();
    int gid = blockIdx.x * blockDim.x + threadIdx.x;
    int v = gid >> 3;
    int t = gid & 7;
    if (v >= N_NODES) return;
    const float* hr = hin + (size_t)v * HID_DIM;
    float a0 = 0.f, a1 = 0.f, a2 = 0.f, a3 = 0.f;
#pragma unroll
    for (int j = 0; j < HID_DIM; j += 4) {
        float4 hv = *(const float4*)(hr + j);
        const float* w = &Ws[j * OUT_DIM + t];
        a0 += hv.x * w[0];   a1 += hv.x * w[8];   a2 += hv.x * w[16];  a3 += hv.x * w[24];
        a0 += hv.y * w[32];  a1 += hv.y * w[40];  a2 += hv.y * w[48];  a3 += hv.y * w[56];
        a0 += hv.z * w[64];  a1 += hv.z * w[72];  a2 += hv.z * w[80];  a3 += hv.z * w[88];
        a0 += hv.w * w[96];  a1 += hv.w * w[104]; a2 += hv.w * w[112]; a3 += hv.w * w[120];
    }
    float s = dinv[v]; s = s * s;   // self-loop norm
    float* h2r = h2 + (size_t)v * OUT_DIM;
    float* outr = out + (size_t)v * OUT_DIM;
    h2r[t]      = a0;  outr[t]      += s * a0;   // stream-ordered, exclusive writer
    h2r[t + 8]  = a1;  outr[t + 8]  += s * a1;
    h2r[t + 16] = a2;  outr[t + 16] += s * a2;
    h2r[t + 24] = a3;  outr[t + 24] += s * a3;
}

// ---------------- edge aggregation: accum[col] += norm * hsrc[row] ----------------
// 8 threads per edge; lane handles 4 consecutive feature components.

__global__ void edge_agg_kernel(const int* __restrict__ ei, const float* __restrict__ ea,
                                const float* __restrict__ dinv,
                                const float* __restrict__ hsrc, float* __restrict__ accum) {
    int gid = blockIdx.x * blockDim.x + threadIdx.x;
    int e = gid >> 3;
    int lane = gid & 7;
    if (e >= N_EDGES) return;
    int row = ei[e];
    int col = ei[N_EDGES + e];
    float norm = dinv[row] * ea[e] * dinv[col];
    float4 hv = *(const float4*)(hsrc + (size_t)row * 32 + lane * 4);
    float* dst = accum + (size_t)col * 32 + lane * 4;
    atomicAdd(dst + 0, norm * hv.x);
    atomicAdd(dst + 1, norm * hv.y);
    atomicAdd(dst + 2, norm * hv.z);
    atomicAdd(dst + 3, norm * hv.w);
}

// ---------------- layer-1 finalize: self-loop + bias + relu + attention logit ----------

__global__ void finalize1_kernel(float* __restrict__ agg, const float* __restrict__ h,
                                 const float* __restrict__ dinv, const float* __restrict__ b,
                                 const float* __restrict__ att_w, float* __restrict__ coef) {
    int v = blockIdx.x * blockDim.x + threadIdx.x;
    if (v >= N_NODES) return;
    float s = dinv[v]; s = s * s;
    float* ar = agg + (size_t)v * HID_DIM;
    const float* hr = h + (size_t)v * HID_DIM;
    float dot = 0.0f;
#pragma unroll
    for (int k = 0; k < HID_DIM; k += 4) {
        float4 av = *(const float4*)(ar + k);
        float4 hv = *(const float4*)(hr + k);
        float4 bv = *(const float4*)(b + k);
        float4 wv = *(const float4*)(att_w + k);
        float e0 = fmaxf(av.x + s * hv.x + bv.x, 0.0f);
        float e1 = fmaxf(av.y + s * hv.y + bv.y, 0.0f);
        float e2 = fmaxf(av.z + s * hv.z + bv.z, 0.0f);
        float e3 = fmaxf(av.w + s * hv.w + bv.w, 0.0f);
        dot += e0 * wv.x + e1 * wv.y + e2 * wv.z + e3 * wv.w;
        float4 ev; ev.x = e0; ev.y = e1; ev.z = e2; ev.w = e3;
        *(float4*)(ar + k) = ev;
    }
    float lr = (dot > 0.0f) ? dot : 0.01f * dot;   // jax.nn.leaky_relu default slope
    coef[v] = expf(lr);
}

// ---------------- attention combine ----------------

__global__ void combine_kernel(const float* __restrict__ emb0, const float* __restrict__ emb1,
                               const float* __restrict__ emb2,
                               const float* __restrict__ coef0, const float* __restrict__ coef1,
                               const float* __restrict__ coef2,
                               float* __restrict__ hmix, float* __restrict__ wout) {
    int v = blockIdx.x * blockDim.x + threadIdx.x;
    if (v >= N_NODES) return;
    float c0 = coef0[v], c1 = coef1[v], c2 = coef2[v];
    float inv = 1.0f / (c0 + c1 + c2);
    float w0 = c0 * inv, w1 = c1 * inv, w2 = c2 * inv;
    wout[v] = w0;
    wout[N_NODES + v] = w1;
    wout[2 * N_NODES + v] = w2;
    const float* e0 = emb0 + (size_t)v * HID_DIM;
    const float* e1 = emb1 + (size_t)v * HID_DIM;
    const float* e2 = emb2 + (size_t)v * HID_DIM;
    float* hm = hmix + (size_t)v * HID_DIM;
#pragma unroll
    for (int k = 0; k < HID_DIM; k += 4) {
        float4 a = *(const float4*)(e0 + k);
        float4 b = *(const float4*)(e1 + k);
        float4 c = *(const float4*)(e2 + k);
        float4 r;
        r.x = w0 * a.x + w1 * b.x + w2 * c.x;
        r.y = w0 * a.y + w1 * b.y + w2 * c.y;
        r.z = w0 * a.z + w1 * b.z + w2 * c.z;
        r.w = w0 * a.w + w1 * b.w + w2 * c.w;
        *(float4*)(hm + k) = r;
    }
}

// ---------------- out init with summed biases ----------------

__global__ void init_out_kernel(const float* __restrict__ bo0, const float* __restrict__ bo1,
                                const float* __restrict__ bo2, float* __restrict__ out) {
    int gid = blockIdx.x * blockDim.x + threadIdx.x;
    if (gid >= N_NODES * OUT_DIM) return;
    int k = gid & 31;
    out[gid] = bo0[k] + bo1[k] + bo2[k];
}

// ---------------- launch ----------------

extern "C" void kernel_launch(void* const* d_in, const int* in_sizes, int n_in,
                              void* d_out, int out_size, void* d_ws, size_t ws_size,
                              hipStream_t stream) {
    // setup_inputs order: per channel c: x, ei, ea, W, b, Wo, bo  (7 each), then att_w
    const float* x[3];  const int* ei[3];  const float* ea[3];
    const float* W[3];  const float* b[3]; const float* Wo[3]; const float* bo[3];
    for (int c = 0; c < 3; c++) {
        x[c]  = (const float*)d_in[7 * c + 0];
        ei[c] = (const int*)  d_in[7 * c + 1];
        ea[c] = (const float*)d_in[7 * c + 2];
        W[c]  = (const float*)d_in[7 * c + 3];
        b[c]  = (const float*)d_in[7 * c + 4];
        Wo[c] = (const float*)d_in[7 * c + 5];
        bo[c] = (const float*)d_in[7 * c + 6];
    }
    const float* att_w = (const float*)d_in[21];
    float* out = (float*)d_out;                 // [N*32] then 3x [N] weights
    float* wout = out + (size_t)N_NODES * OUT_DIM;

    // workspace layout (floats)
    float* ws = (float*)d_ws;
    float* dinv  = ws;                                   // 3*N (deg then dinv in-place)
    float* emb   = dinv + 3 * (size_t)N_NODES;           // 3*N*32
    float* coef  = emb + 3 * (size_t)N_NODES * HID_DIM;  // 3*N
    float* h_tmp = coef + 3 * (size_t)N_NODES;           // N*32
    float* hmix  = h_tmp + (size_t)N_NODES * HID_DIM;    // N*32
    float* h2    = hmix + (size_t)N_NODES * HID_DIM;     // N*32

    const int B = 256;
    const int gN   = (N_NODES + B - 1) / B;
    const int g3N  = (3 * N_NODES + B - 1) / B;
    const int gE   = (N_EDGES + B - 1) / B;
    const int gE8  = (N_EDGES * 8 + B - 1) / B;
    const int gN8  = (N_NODES * 8 + B - 1) / B;
    const int gN32 = (N_NODES * 32 + B - 1) / B;

    // degrees -> dinv
    init_deg_kernel<<<g3N, B, 0, stream>>>(dinv, 3 * N_NODES);
    for (int c = 0; c < 3; c++)
        deg_edges_kernel<<<gE, B, 0, stream>>>(ei[c], ea[c], dinv + (size_t)c * N_NODES);
    make_dinv_kernel<<<g3N, B, 0, stream>>>(dinv, 3 * N_NODES);

    // layer 1 per channel
    for (int c = 0; c < 3; c++) {
        float* emb_c  = emb + (size_t)c * N_NODES * HID_DIM;
        float* dinv_c = dinv + (size_t)c * N_NODES;
        matmul_in_kernel<<<gN8, B, 0, stream>>>(x[c], W[c], h_tmp);
        hipMemsetAsync(emb_c, 0, (size_t)N_NODES * HID_DIM * sizeof(float), stream);
        edge_agg_kernel<<<gE8, B, 0, stream>>>(ei[c], ea[c], dinv_c, h_tmp, emb_c);
        finalize1_kernel<<<gN, B, 0, stream>>>(emb_c, h_tmp, dinv_c, b[c], att_w,
                                               coef + (size_t)c * N_NODES);
    }

    // attention combine
    combine_kernel<<<gN, B, 0, stream>>>(emb, emb + (size_t)N_NODES * HID_DIM,
                                         emb + 2 * (size_t)N_NODES * HID_DIM,
                                         coef, coef + N_NODES, coef + 2 * N_NODES,
                                         hmix, wout);

    // layer 2: out = sum_c gcn_conv(hmix, ei_c, ea_c, Wo_c, bo_c)
    init_out_kernel<<<gN32, B, 0, stream>>>(bo[0], bo[1], bo[2], out);
    for (int c = 0; c < 3; c++) {
        float* dinv_c = dinv + (size_t)c * N_NODES;
        matmul_hid_kernel<<<gN8, B, 0, stream>>>(hmix, Wo[c], dinv_c, h2, out);
        edge_agg_kernel<<<gE8, B, 0, stream>>>(ei[c], ea[c], dinv_c, h2, out);
    }
}

// Round 2
// 1663.589 us; speedup vs baseline: 2.7187x; 2.7187x over previous
//
#include <hip/hip_runtime.h>

#define N_NODES 100000
#define N_EDGES 1600000
#define IN_DIM  128
#define HID_DIM 32
#define OUT_DIM 32

// ---------------- degree / norm ----------------

__global__ void init_deg_kernel(float* deg, int n) {
    int i = blockIdx.x * blockDim.x + threadIdx.x;
    if (i < n) deg[i] = 1.0f;   // self-loop weight
}

__global__ void deg_edges_kernel(const int* __restrict__ ei, const float* __restrict__ ea,
                                 float* __restrict__ deg) {
    int e = blockIdx.x * blockDim.x + threadIdx.x;
    if (e < N_EDGES) {
        int col = ei[N_EDGES + e];
        atomicAdd(&deg[col], ea[e]);
    }
}

__global__ void make_dinv_kernel(float* deg, int n) {
    int i = blockIdx.x * blockDim.x + threadIdx.x;
    if (i < n) {
        float d = deg[i];
        deg[i] = (d > 0.0f) ? rsqrtf(d) : 0.0f;
    }
}

// ---------------- CSR build ----------------

__global__ void hist_kernel(const int* __restrict__ ei, int* __restrict__ count) {
    int e = blockIdx.x * blockDim.x + threadIdx.x;
    if (e < N_EDGES) atomicAdd(&count[ei[N_EDGES + e]], 1);
}

// single-block exclusive scan: row_ptr[0]=0, row_ptr[i+1]=sum(counts[0..i])
__global__ void scan_kernel(const int* __restrict__ counts, int* __restrict__ row_ptr, int n) {
    __shared__ int wsum[16];
    __shared__ int chunk_total;
    int tid = threadIdx.x;
    int lane = tid & 63, wave = tid >> 6;
    int carry = 0;
    for (int base = 0; base < n; base += 1024) {
        int i = base + tid;
        int x = (i < n) ? counts[i] : 0;
        // wave-level inclusive scan (64 lanes)
        for (int d = 1; d < 64; d <<= 1) {
            int t = __shfl_up(x, d, 64);
            if (lane >= d) x += t;
        }
        if (lane == 63) wsum[wave] = x;
        __syncthreads();
        if (wave == 0 && lane < 16) {
            int w = wsum[lane];
            for (int d = 1; d < 16; d <<= 1) {
                int t = __shfl_up(w, d, 64);
                if (lane >= d) w += t;
            }
            wsum[lane] = w;
            if (lane == 15) chunk_total = w;
        }
        __syncthreads();
        int waveoff = (wave > 0) ? wsum[wave - 1] : 0;
        if (i < n) row_ptr[i + 1] = carry + waveoff + x;
        if (i == 0) row_ptr[0] = 0;
        carry += chunk_total;
        __syncthreads();   // protect wsum/chunk_total for next chunk
    }
}

// scatter edges into CSR slots, with precomputed norm
__global__ void scatter_kernel(const int* __restrict__ ei, const float* __restrict__ ea,
                               const float* __restrict__ dinv,
                               const int* __restrict__ row_ptr, int* __restrict__ fill,
                               int2* __restrict__ csr) {
    int e = blockIdx.x * blockDim.x + threadIdx.x;
    if (e >= N_EDGES) return;
    int row = ei[e];
    int col = ei[N_EDGES + e];
    float norm = dinv[row] * ea[e] * dinv[col];
    int slot = row_ptr[col] + atomicAdd(&fill[col], 1);
    csr[slot] = make_int2(row, __float_as_int(norm));
}

// ---------------- matmul: x[N,128] @ W[128,32] -> h[N,32] ----------------
// 8 threads per node; thread t computes outputs {t, t+8, t+16, t+24}.

__global__ void matmul_in_kernel(const float* __restrict__ x, const float* __restrict__ W,
                                 float* __restrict__ h) {
    __shared__ float Ws[IN_DIM * HID_DIM];   // 16 KB
    for (int i = threadIdx.x; i < IN_DIM * HID_DIM; i += blockDim.x) Ws[i] = W[i];
    __syncthreads();
    int gid = blockIdx.x * blockDim.x + threadIdx.x;
    int v = gid >> 3;
    int t = gid & 7;
    if (v >= N_NODES) return;
    const float* xr = x + (size_t)v * IN_DIM;
    float a0 = 0.f, a1 = 0.f, a2 = 0.f, a3 = 0.f;
#pragma unroll
    for (int j = 0; j < IN_DIM; j += 4) {
        float4 xv = *(const float4*)(xr + j);
        const float* w = &Ws[j * HID_DIM + t];
        a0 += xv.x * w[0];   a1 += xv.x * w[8];   a2 += xv.x * w[16];  a3 += xv.x * w[24];
        a0 += xv.y * w[32];  a1 += xv.y * w[40];  a2 += xv.y * w[48];  a3 += xv.y * w[56];
        a0 += xv.z * w[64];  a1 += xv.z * w[72];  a2 += xv.z * w[80];  a3 += xv.z * w[88];
        a0 += xv.w * w[96];  a1 += xv.w * w[104]; a2 += xv.w * w[112]; a3 += xv.w * w[120];
    }
    float* hr = h + (size_t)v * HID_DIM;
    hr[t] = a0; hr[t + 8] = a1; hr[t + 16] = a2; hr[t + 24] = a3;
}

// ---------------- matmul: hmix[N,32] @ Wo[32,32] -> h2[N,32], plus self-loop into out ----

__global__ void matmul_hid_kernel(const float* __restrict__ hin, const float* __restrict__ Wo,
                                  const float* __restrict__ dinv,
                                  float* __restrict__ h2, float* __restrict__ out) {
    __shared__ float Ws[HID_DIM * OUT_DIM];  // 4 KB
    for (int i = threadIdx.x; i < HID_DIM * OUT_DIM; i += blockDim.x) Ws[i] = Wo[i];
    __syncthreads();
    int gid = blockIdx.x * blockDim.x + threadIdx.x;
    int v = gid >> 3;
    int t = gid & 7;
    if (v >= N_NODES) return;
    const float* hr = hin + (size_t)v * HID_DIM;
    float a0 = 0.f, a1 = 0.f, a2 = 0.f, a3 = 0.f;
#pragma unroll
    for (int j = 0; j < HID_DIM; j += 4) {
        float4 hv = *(const float4*)(hr + j);
        const float* w = &Ws[j * OUT_DIM + t];
        a0 += hv.x * w[0];   a1 += hv.x * w[8];   a2 += hv.x * w[16];  a3 += hv.x * w[24];
        a0 += hv.y * w[32];  a1 += hv.y * w[40];  a2 += hv.y * w[48];  a3 += hv.y * w[56];
        a0 += hv.z * w[64];  a1 += hv.z * w[72];  a2 += hv.z * w[80];  a3 += hv.z * w[88];
        a0 += hv.w * w[96];  a1 += hv.w * w[104]; a2 += hv.w * w[112]; a3 += hv.w * w[120];
    }
    float s = dinv[v]; s = s * s;   // self-loop norm
    float* h2r = h2 + (size_t)v * OUT_DIM;
    float* outr = out + (size_t)v * OUT_DIM;
    h2r[t]      = a0;  outr[t]      += s * a0;   // exclusive writer, stream-ordered
    h2r[t + 8]  = a1;  outr[t + 8]  += s * a1;
    h2r[t + 16] = a2;  outr[t + 16] += s * a2;
    h2r[t + 24] = a3;  outr[t + 24] += s * a3;
}

// ---------------- layer-1 gather + finalize (self-loop+bias+relu+attention logit) ----

__global__ void gather_finalize_kernel(const int* __restrict__ row_ptr,
                                       const int2* __restrict__ csr,
                                       const float* __restrict__ h,
                                       const float* __restrict__ dinv,
                                       const float* __restrict__ b,
                                       const float* __restrict__ att_w,
                                       float* __restrict__ emb,
                                       float* __restrict__ coef) {
    int gid = blockIdx.x * blockDim.x + threadIdx.x;
    int v = gid >> 3;
    int t = gid & 7;
    if (v >= N_NODES) return;
    int beg = row_ptr[v], end = row_ptr[v + 1];
    float a0 = 0.f, a1 = 0.f, a2 = 0.f, a3 = 0.f;
    for (int e = beg; e < end; e++) {
        int2 p = csr[e];
        float norm = __int_as_float(p.y);
        float4 hv = *(const float4*)(h + (size_t)p.x * 32 + t * 4);
        a0 += norm * hv.x; a1 += norm * hv.y; a2 += norm * hv.z; a3 += norm * hv.w;
    }
    float s = dinv[v]; s = s * s;
    float4 hv = *(const float4*)(h + (size_t)v * 32 + t * 4);
    float4 bv = *(const float4*)(b + t * 4);
    float e0 = fmaxf(a0 + s * hv.x + bv.x, 0.f);
    float e1 = fmaxf(a1 + s * hv.y + bv.y, 0.f);
    float e2 = fmaxf(a2 + s * hv.z + bv.z, 0.f);
    float e3 = fmaxf(a3 + s * hv.w + bv.w, 0.f);
    float4 ev; ev.x = e0; ev.y = e1; ev.z = e2; ev.w = e3;
    *(float4*)(emb + (size_t)v * 32 + t * 4) = ev;
    float4 wv = *(const float4*)(att_w + t * 4);
    float dot = e0 * wv.x + e1 * wv.y + e2 * wv.z + e3 * wv.w;
    dot += __shfl_xor(dot, 1, 64);
    dot += __shfl_xor(dot, 2, 64);
    dot += __shfl_xor(dot, 4, 64);
    if (t == 0) {
        float lr = (dot > 0.0f) ? dot : 0.01f * dot;
        coef[v] = expf(lr);
    }
}

// ---------------- layer-2 gather: out += aggregated h2 ----------------

__global__ void gather_add_kernel(const int* __restrict__ row_ptr,
                                  const int2* __restrict__ csr,
                                  const float* __restrict__ h2,
                                  float* __restrict__ out) {
    int gid = blockIdx.x * blockDim.x + threadIdx.x;
    int v = gid >> 3;
    int t = gid & 7;
    if (v >= N_NODES) return;
    int beg = row_ptr[v], end = row_ptr[v + 1];
    float a0 = 0.f, a1 = 0.f, a2 = 0.f, a3 = 0.f;
    for (int e = beg; e < end; e++) {
        int2 p = csr[e];
        float norm = __int_as_float(p.y);
        float4 hv = *(const float4*)(h2 + (size_t)p.x * 32 + t * 4);
        a0 += norm * hv.x; a1 += norm * hv.y; a2 += norm * hv.z; a3 += norm * hv.w;
    }
    float* o = out + (size_t)v * 32 + t * 4;
    float4 ov = *(float4*)o;
    ov.x += a0; ov.y += a1; ov.z += a2; ov.w += a3;
    *(float4*)o = ov;
}

// ---------------- attention combine ----------------

__global__ void combine_kernel(const float* __restrict__ emb0, const float* __restrict__ emb1,
                               const float* __restrict__ emb2,
                               const float* __restrict__ coef0, const float* __restrict__ coef1,
                               const float* __restrict__ coef2,
                               float* __restrict__ hmix, float* __restrict__ wout) {
    int v = blockIdx.x * blockDim.x + threadIdx.x;
    if (v >= N_NODES) return;
    float c0 = coef0[v], c1 = coef1[v], c2 = coef2[v];
    float inv = 1.0f / (c0 + c1 + c2);
    float w0 = c0 * inv, w1 = c1 * inv, w2 = c2 * inv;
    wout[v] = w0;
    wout[N_NODES + v] = w1;
    wout[2 * N_NODES + v] = w2;
    const float* e0 = emb0 + (size_t)v * HID_DIM;
    const float* e1 = emb1 + (size_t)v * HID_DIM;
    const float* e2 = emb2 + (size_t)v * HID_DIM;
    float* hm = hmix + (size_t)v * HID_DIM;
#pragma unroll
    for (int k = 0; k < HID_DIM; k += 4) {
        float4 a = *(const float4*)(e0 + k);
        float4 b = *(const float4*)(e1 + k);
        float4 c = *(const float4*)(e2 + k);
        float4 r;
        r.x = w0 * a.x + w1 * b.x + w2 * c.x;
        r.y = w0 * a.y + w1 * b.y + w2 * c.y;
        r.z = w0 * a.z + w1 * b.z + w2 * c.z;
        r.w = w0 * a.w + w1 * b.w + w2 * c.w;
        *(float4*)(hm + k) = r;
    }
}

// ---------------- out init with summed biases ----------------

__global__ void init_out_kernel(const float* __restrict__ bo0, const float* __restrict__ bo1,
                                const float* __restrict__ bo2, float* __restrict__ out) {
    int gid = blockIdx.x * blockDim.x + threadIdx.x;
    if (gid >= N_NODES * OUT_DIM) return;
    int k = gid & 31;
    out[gid] = bo0[k] + bo1[k] + bo2[k];
}

// ---------------- launch ----------------

extern "C" void kernel_launch(void* const* d_in, const int* in_sizes, int n_in,
                              void* d_out, int out_size, void* d_ws, size_t ws_size,
                              hipStream_t stream) {
    const float* x[3];  const int* ei[3];  const float* ea[3];
    const float* W[3];  const float* b[3]; const float* Wo[3]; const float* bo[3];
    for (int c = 0; c < 3; c++) {
        x[c]  = (const float*)d_in[7 * c + 0];
        ei[c] = (const int*)  d_in[7 * c + 1];
        ea[c] = (const float*)d_in[7 * c + 2];
        W[c]  = (const float*)d_in[7 * c + 3];
        b[c]  = (const float*)d_in[7 * c + 4];
        Wo[c] = (const float*)d_in[7 * c + 5];
        bo[c] = (const float*)d_in[7 * c + 6];
    }
    const float* att_w = (const float*)d_in[21];
    float* out = (float*)d_out;                 // [N*32] then 3x [N] weights
    float* wout = out + (size_t)N_NODES * OUT_DIM;

    // workspace layout (4-byte units)
    float* ws = (float*)d_ws;
    float* dinv    = ws;                                         // 3N
    int*   row_ptr = (int*)(dinv + 3 * (size_t)N_NODES);         // 3*(N+1), +1 pad
    int*   fill    = row_ptr + 3 * (N_NODES + 1) + 1;            // 3N  (also histogram counts)
    int2*  csr     = (int2*)(fill + 3 * (size_t)N_NODES);        // 3E pairs (8B-aligned)
    float* emb     = (float*)(csr + 3 * (size_t)N_EDGES);        // 3*N*32
    float* coef    = emb + 3 * (size_t)N_NODES * HID_DIM;        // 3N
    float* h_tmp   = coef + 3 * (size_t)N_NODES;                 // N*32 (reused as h2)
    float* hmix    = h_tmp + (size_t)N_NODES * HID_DIM;          // N*32
    float* h2      = h_tmp;                                      // alias: dead after layer 1

    const int B = 256;
    const int gN   = (N_NODES + B - 1) / B;
    const int g3N  = (3 * N_NODES + B - 1) / B;
    const int gE   = (N_EDGES + B - 1) / B;
    const int gN8  = (N_NODES * 8 + B - 1) / B;
    const int gN32 = (N_NODES * 32 + B - 1) / B;

    // degrees -> dinv
    init_deg_kernel<<<g3N, B, 0, stream>>>(dinv, 3 * N_NODES);
    for (int c = 0; c < 3; c++)
        deg_edges_kernel<<<gE, B, 0, stream>>>(ei[c], ea[c], dinv + (size_t)c * N_NODES);
    make_dinv_kernel<<<g3N, B, 0, stream>>>(dinv, 3 * N_NODES);

    // CSR build per channel (reused by both layers)
    hipMemsetAsync(fill, 0, 3 * (size_t)N_NODES * sizeof(int), stream);
    for (int c = 0; c < 3; c++)
        hist_kernel<<<gE, B, 0, stream>>>(ei[c], fill + (size_t)c * N_NODES);
    for (int c = 0; c < 3; c++)
        scan_kernel<<<1, 1024, 0, stream>>>(fill + (size_t)c * N_NODES,
                                            row_ptr + (size_t)c * (N_NODES + 1), N_NODES);
    hipMemsetAsync(fill, 0, 3 * (size_t)N_NODES * sizeof(int), stream);
    for (int c = 0; c < 3; c++)
        scatter_kernel<<<gE, B, 0, stream>>>(ei[c], ea[c], dinv + (size_t)c * N_NODES,
                                             row_ptr + (size_t)c * (N_NODES + 1),
                                             fill + (size_t)c * N_NODES,
                                             csr + (size_t)c * N_EDGES);

    // layer 1 per channel: matmul -> gather+finalize
    for (int c = 0; c < 3; c++) {
        matmul_in_kernel<<<gN8, B, 0, stream>>>(x[c], W[c], h_tmp);
        gather_finalize_kernel<<<gN8, B, 0, stream>>>(
            row_ptr + (size_t)c * (N_NODES + 1), csr + (size_t)c * N_EDGES,
            h_tmp, dinv + (size_t)c * N_NODES, b[c], att_w,
            emb + (size_t)c * N_NODES * HID_DIM, coef + (size_t)c * N_NODES);
    }

    // attention combine
    combine_kernel<<<gN, B, 0, stream>>>(emb, emb + (size_t)N_NODES * HID_DIM,
                                         emb + 2 * (size_t)N_NODES * HID_DIM,
                                         coef, coef + N_NODES, coef + 2 * N_NODES,
                                         hmix, wout);

    // layer 2: out = sum_c gcn_conv(hmix, ei_c, ea_c, Wo_c, bo_c)
    init_out_kernel<<<gN32, B, 0, stream>>>(bo[0], bo[1], bo[2], out);
    for (int c = 0; c < 3; c++) {
        matmul_hid_kernel<<<gN8, B, 0, stream>>>(hmix, Wo[c], dinv + (size_t)c * N_NODES,
                                                 h2, out);
        gather_add_kernel<<<gN8, B, 0, stream>>>(row_ptr + (size_t)c * (N_NODES + 1),
                                                 csr + (size_t)c * N_EDGES, h2, out);
    }
}

// Round 3
// 1367.165 us; speedup vs baseline: 3.3082x; 1.2168x over previous
//
#include <hip/hip_runtime.h>

#define N_NODES 100000
#define N_EDGES 1600000
#define IN_DIM  128
#define HID_DIM 32
#define OUT_DIM 32

#define SCAN_B    256
#define SCAN_VT   8
#define SCAN_CHUNK (SCAN_B * SCAN_VT)   // 2048
#define SCAN_N    (3 * N_NODES)          // 300000 (multiple of 8)
#define SCAN_G    ((SCAN_N + SCAN_CHUNK - 1) / SCAN_CHUNK)  // 147

// ---------------- degree / norm ----------------

__global__ void init_deg_kernel(float* deg, int n) {
    int i = blockIdx.x * blockDim.x + threadIdx.x;
    if (i < n) deg[i] = 1.0f;   // self-loop weight
}

// fused: histogram (CSR counts) + weighted degree, one pass over edges
__global__ void hist_deg_kernel(const int* __restrict__ ei, const float* __restrict__ ea,
                                int* __restrict__ count, float* __restrict__ deg) {
    int e = blockIdx.x * blockDim.x + threadIdx.x;
    if (e < N_EDGES) {
        int col = ei[N_EDGES + e];
        atomicAdd(&count[col], 1);
        atomicAdd(&deg[col], ea[e]);
    }
}

__global__ void make_dinv_kernel(float* deg, int n) {
    int i = blockIdx.x * blockDim.x + threadIdx.x;
    if (i < n) {
        float d = deg[i];
        deg[i] = (d > 0.0f) ? rsqrtf(d) : 0.0f;
    }
}

// ---------------- parallel 3-phase scan over counts[3N] -> row_ptr[3N+1] --------
// Single scan of concatenated per-channel counts: channel c's CSR base offset
// (c * N_EDGES) emerges automatically since each channel has exactly N_EDGES edges.

__global__ void scan1_kernel(const int* __restrict__ counts, int* __restrict__ rp1,
                             int* __restrict__ blocksum) {
    __shared__ int wsum[4];
    int tid = threadIdx.x;
    int base = blockIdx.x * SCAN_CHUNK + tid * SCAN_VT;
    int vals[SCAN_VT];
    int tsum = 0;
    if (base < SCAN_N) {        // SCAN_N multiple of 8 -> all-or-nothing per thread
        int4 v0 = *(const int4*)(counts + base);
        int4 v1 = *(const int4*)(counts + base + 4);
        vals[0] = v0.x; vals[1] = v0.y; vals[2] = v0.z; vals[3] = v0.w;
        vals[4] = v1.x; vals[5] = v1.y; vals[6] = v1.z; vals[7] = v1.w;
#pragma unroll
        for (int k = 0; k < SCAN_VT; k++) tsum += vals[k];
    } else {
#pragma unroll
        for (int k = 0; k < SCAN_VT; k++) vals[k] = 0;
    }
    int lane = tid & 63, wave = tid >> 6;
    int x = tsum;
    for (int d = 1; d < 64; d <<= 1) {
        int t = __shfl_up(x, d, 64);
        if (lane >= d) x += t;
    }
    if (lane == 63) wsum[wave] = x;
    __syncthreads();
    int waveoff = 0;
    for (int w = 0; w < wave; w++) waveoff += wsum[w];
    int run = waveoff + x - tsum;     // exclusive prefix for this thread (block-local)
    if (base < SCAN_N) {
#pragma unroll
        for (int k = 0; k < SCAN_VT; k++) {
            run += vals[k];
            rp1[base + k + 1] = run;  // block-local inclusive
        }
    }
    if (tid == SCAN_B - 1) blocksum[blockIdx.x] = waveoff + x;  // block total
}

__global__ void scan2_kernel(int* __restrict__ blocksum) {   // G <= 256
    __shared__ int wsum[4];
    int tid = threadIdx.x;
    int lane = tid & 63, wave = tid >> 6;
    int v = (tid < SCAN_G) ? blocksum[tid] : 0;
    int x = v;
    for (int d = 1; d < 64; d <<= 1) {
        int t = __shfl_up(x, d, 64);
        if (lane >= d) x += t;
    }
    if (lane == 63) wsum[wave] = x;
    __syncthreads();
    int waveoff = 0;
    for (int w = 0; w < wave; w++) waveoff += wsum[w];
    if (tid < SCAN_G) blocksum[tid] = waveoff + x - v;   // exclusive
}

__global__ void scan3_kernel(int* __restrict__ rp1, const int* __restrict__ blocksum) {
    int i = blockIdx.x * blockDim.x + threadIdx.x;
    if (i < SCAN_N) rp1[i + 1] += blocksum[i / SCAN_CHUNK];
    if (i == 0) rp1[0] = 0;
}

// scatter edges into CSR slots, with precomputed norm
__global__ void scatter_kernel(const int* __restrict__ ei, const float* __restrict__ ea,
                               const float* __restrict__ dinv,
                               const int* __restrict__ row_ptr, int* __restrict__ fill,
                               int2* __restrict__ csr) {
    int e = blockIdx.x * blockDim.x + threadIdx.x;
    if (e >= N_EDGES) return;
    int row = ei[e];
    int col = ei[N_EDGES + e];
    float norm = dinv[row] * ea[e] * dinv[col];
    int slot = row_ptr[col] + atomicAdd(&fill[col], 1);  // slot is global (concat csr)
    csr[slot] = make_int2(row, __float_as_int(norm));
}

// ---------------- matmul: x[N,128] @ W[128,32] -> h[N,32] ----------------

__global__ void matmul_in_kernel(const float* __restrict__ x, const float* __restrict__ W,
                                 float* __restrict__ h) {
    __shared__ float Ws[IN_DIM * HID_DIM];   // 16 KB
    for (int i = threadIdx.x; i < IN_DIM * HID_DIM; i += blockDim.x) Ws[i] = W[i];
    __syncthreads();
    int gid = blockIdx.x * blockDim.x + threadIdx.x;
    int v = gid >> 3;
    int t = gid & 7;
    if (v >= N_NODES) return;
    const float* xr = x + (size_t)v * IN_DIM;
    float a0 = 0.f, a1 = 0.f, a2 = 0.f, a3 = 0.f;
#pragma unroll
    for (int j = 0; j < IN_DIM; j += 4) {
        float4 xv = *(const float4*)(xr + j);
        const float* w = &Ws[j * HID_DIM + t];
        a0 += xv.x * w[0];   a1 += xv.x * w[8];   a2 += xv.x * w[16];  a3 += xv.x * w[24];
        a0 += xv.y * w[32];  a1 += xv.y * w[40];  a2 += xv.y * w[48];  a3 += xv.y * w[56];
        a0 += xv.z * w[64];  a1 += xv.z * w[72];  a2 += xv.z * w[80];  a3 += xv.z * w[88];
        a0 += xv.w * w[96];  a1 += xv.w * w[104]; a2 += xv.w * w[112]; a3 += xv.w * w[120];
    }
    float* hr = h + (size_t)v * HID_DIM;
    hr[t] = a0; hr[t + 8] = a1; hr[t + 16] = a2; hr[t + 24] = a3;
}

// ---------------- matmul: hmix[N,32] @ Wo[32,32] -> h2[N,32], + self-loop into out ----

__global__ void matmul_hid_kernel(const float* __restrict__ hin, const float* __restrict__ Wo,
                                  const float* __restrict__ dinv,
                                  float* __restrict__ h2, float* __restrict__ out) {
    __shared__ float Ws[HID_DIM * OUT_DIM];  // 4 KB
    for (int i = threadIdx.x; i < HID_DIM * OUT_DIM; i += blockDim.x) Ws[i] = Wo[i];
    __syncthreads();
    int gid = blockIdx.x * blockDim.x + threadIdx.x;
    int v = gid >> 3;
    int t = gid & 7;
    if (v >= N_NODES) return;
    const float* hr = hin + (size_t)v * HID_DIM;
    float a0 = 0.f, a1 = 0.f, a2 = 0.f, a3 = 0.f;
#pragma unroll
    for (int j = 0; j < HID_DIM; j += 4) {
        float4 hv = *(const float4*)(hr + j);
        const float* w = &Ws[j * OUT_DIM + t];
        a0 += hv.x * w[0];   a1 += hv.x * w[8];   a2 += hv.x * w[16];  a3 += hv.x * w[24];
        a0 += hv.y * w[32];  a1 += hv.y * w[40];  a2 += hv.y * w[48];  a3 += hv.y * w[56];
        a0 += hv.z * w[64];  a1 += hv.z * w[72];  a2 += hv.z * w[80];  a3 += hv.z * w[88];
        a0 += hv.w * w[96];  a1 += hv.w * w[104]; a2 += hv.w * w[112]; a3 += hv.w * w[120];
    }
    float s = dinv[v]; s = s * s;   // self-loop norm
    float* h2r = h2 + (size_t)v * OUT_DIM;
    float* outr = out + (size_t)v * OUT_DIM;
    h2r[t]      = a0;  outr[t]      += s * a0;   // exclusive writer, stream-ordered
    h2r[t + 8]  = a1;  outr[t + 8]  += s * a1;
    h2r[t + 16] = a2;  outr[t + 16] += s * a2;
    h2r[t + 24] = a3;  outr[t + 24] += s * a3;
}

// ---------------- layer-1 gather + finalize ----------------

__global__ void gather_finalize_kernel(const int* __restrict__ row_ptr,
                                       const int2* __restrict__ csr,
                                       const float* __restrict__ h,
                                       const float* __restrict__ dinv,
                                       const float* __restrict__ b,
                                       const float* __restrict__ att_w,
                                       float* __restrict__ emb,
                                       float* __restrict__ coef) {
    int gid = blockIdx.x * blockDim.x + threadIdx.x;
    int v = gid >> 3;
    int t = gid & 7;
    if (v >= N_NODES) return;
    int beg = row_ptr[v], end = row_ptr[v + 1];
    float a0 = 0.f, a1 = 0.f, a2 = 0.f, a3 = 0.f;
    for (int e = beg; e < end; e++) {
        int2 p = csr[e];
        float norm = __int_as_float(p.y);
        float4 hv = *(const float4*)(h + (size_t)p.x * 32 + t * 4);
        a0 += norm * hv.x; a1 += norm * hv.y; a2 += norm * hv.z; a3 += norm * hv.w;
    }
    float s = dinv[v]; s = s * s;
    float4 hv = *(const float4*)(h + (size_t)v * 32 + t * 4);
    float4 bv = *(const float4*)(b + t * 4);
    float e0 = fmaxf(a0 + s * hv.x + bv.x, 0.f);
    float e1 = fmaxf(a1 + s * hv.y + bv.y, 0.f);
    float e2 = fmaxf(a2 + s * hv.z + bv.z, 0.f);
    float e3 = fmaxf(a3 + s * hv.w + bv.w, 0.f);
    float4 ev; ev.x = e0; ev.y = e1; ev.z = e2; ev.w = e3;
    *(float4*)(emb + (size_t)v * 32 + t * 4) = ev;
    float4 wv = *(const float4*)(att_w + t * 4);
    float dot = e0 * wv.x + e1 * wv.y + e2 * wv.z + e3 * wv.w;
    dot += __shfl_xor(dot, 1, 64);
    dot += __shfl_xor(dot, 2, 64);
    dot += __shfl_xor(dot, 4, 64);
    if (t == 0) {
        float lr = (dot > 0.0f) ? dot : 0.01f * dot;
        coef[v] = expf(lr);
    }
}

// ---------------- layer-2 gather: out += aggregated h2 ----------------

__global__ void gather_add_kernel(const int* __restrict__ row_ptr,
                                  const int2* __restrict__ csr,
                                  const float* __restrict__ h2,
                                  float* __restrict__ out) {
    int gid = blockIdx.x * blockDim.x + threadIdx.x;
    int v = gid >> 3;
    int t = gid & 7;
    if (v >= N_NODES) return;
    int beg = row_ptr[v], end = row_ptr[v + 1];
    float a0 = 0.f, a1 = 0.f, a2 = 0.f, a3 = 0.f;
    for (int e = beg; e < end; e++) {
        int2 p = csr[e];
        float norm = __int_as_float(p.y);
        float4 hv = *(const float4*)(h2 + (size_t)p.x * 32 + t * 4);
        a0 += norm * hv.x; a1 += norm * hv.y; a2 += norm * hv.z; a3 += norm * hv.w;
    }
    float* o = out + (size_t)v * 32 + t * 4;
    float4 ov = *(float4*)o;
    ov.x += a0; ov.y += a1; ov.z += a2; ov.w += a3;
    *(float4*)o = ov;
}

// ---------------- attention combine ----------------

__global__ void combine_kernel(const float* __restrict__ emb0, const float* __restrict__ emb1,
                               const float* __restrict__ emb2,
                               const float* __restrict__ coef0, const float* __restrict__ coef1,
                               const float* __restrict__ coef2,
                               float* __restrict__ hmix, float* __restrict__ wout) {
    int v = blockIdx.x * blockDim.x + threadIdx.x;
    if (v >= N_NODES) return;
    float c0 = coef0[v], c1 = coef1[v], c2 = coef2[v];
    float inv = 1.0f / (c0 + c1 + c2);
    float w0 = c0 * inv, w1 = c1 * inv, w2 = c2 * inv;
    wout[v] = w0;
    wout[N_NODES + v] = w1;
    wout[2 * N_NODES + v] = w2;
    const float* e0 = emb0 + (size_t)v * HID_DIM;
    const float* e1 = emb1 + (size_t)v * HID_DIM;
    const float* e2 = emb2 + (size_t)v * HID_DIM;
    float* hm = hmix + (size_t)v * HID_DIM;
#pragma unroll
    for (int k = 0; k < HID_DIM; k += 4) {
        float4 a = *(const float4*)(e0 + k);
        float4 b = *(const float4*)(e1 + k);
        float4 c = *(const float4*)(e2 + k);
        float4 r;
        r.x = w0 * a.x + w1 * b.x + w2 * c.x;
        r.y = w0 * a.y + w1 * b.y + w2 * c.y;
        r.z = w0 * a.z + w1 * b.z + w2 * c.z;
        r.w = w0 * a.w + w1 * b.w + w2 * c.w;
        *(float4*)(hm + k) = r;
    }
}

// ---------------- out init with summed biases ----------------

__global__ void init_out_kernel(const float* __restrict__ bo0, const float* __restrict__ bo1,
                                const float* __restrict__ bo2, float* __restrict__ out) {
    int gid = blockIdx.x * blockDim.x + threadIdx.x;
    if (gid >= N_NODES * OUT_DIM) return;
    int k = gid & 31;
    out[gid] = bo0[k] + bo1[k] + bo2[k];
}

// ---------------- launch ----------------

extern "C" void kernel_launch(void* const* d_in, const int* in_sizes, int n_in,
                              void* d_out, int out_size, void* d_ws, size_t ws_size,
                              hipStream_t stream) {
    const float* x[3];  const int* ei[3];  const float* ea[3];
    const float* W[3];  const float* b[3]; const float* Wo[3]; const float* bo[3];
    for (int c = 0; c < 3; c++) {
        x[c]  = (const float*)d_in[7 * c + 0];
        ei[c] = (const int*)  d_in[7 * c + 1];
        ea[c] = (const float*)d_in[7 * c + 2];
        W[c]  = (const float*)d_in[7 * c + 3];
        b[c]  = (const float*)d_in[7 * c + 4];
        Wo[c] = (const float*)d_in[7 * c + 5];
        bo[c] = (const float*)d_in[7 * c + 6];
    }
    const float* att_w = (const float*)d_in[21];
    float* out = (float*)d_out;                 // [N*32] then 3x [N] weights
    float* wout = out + (size_t)N_NODES * OUT_DIM;

    // workspace layout (4-byte units; keep fill/csr 16B/8B aligned)
    float* ws = (float*)d_ws;
    float* dinv     = ws;                                        // 3N
    int*   row_ptr  = (int*)(dinv + 3 * (size_t)N_NODES);        // 3N+4 (entry [3N] used)
    int*   fill     = row_ptr + 3 * N_NODES + 4;                 // 3N (counts, then fill)
    int*   blocksum = fill + 3 * (size_t)N_NODES;                // 160
    int2*  csr      = (int2*)(blocksum + 160);                   // 3E pairs, global slots
    float* emb      = (float*)(csr + 3 * (size_t)N_EDGES);       // 3*N*32
    float* coef     = emb + 3 * (size_t)N_NODES * HID_DIM;       // 3N
    float* h_tmp    = coef + 3 * (size_t)N_NODES;                // N*32 (reused as h2)
    float* hmix     = h_tmp + (size_t)N_NODES * HID_DIM;         // N*32
    float* h2       = h_tmp;                                     // alias: dead after layer 1

    const int B = 256;
    const int gN   = (N_NODES + B - 1) / B;
    const int g3N  = (3 * N_NODES + B - 1) / B;
    const int gE   = (N_EDGES + B - 1) / B;
    const int gN8  = (N_NODES * 8 + B - 1) / B;
    const int gN32 = (N_NODES * 32 + B - 1) / B;

    // degrees + histogram (fused single pass over edges)
    init_deg_kernel<<<g3N, B, 0, stream>>>(dinv, 3 * N_NODES);
    hipMemsetAsync(fill, 0, 3 * (size_t)N_NODES * sizeof(int), stream);
    for (int c = 0; c < 3; c++)
        hist_deg_kernel<<<gE, B, 0, stream>>>(ei[c], ea[c], fill + (size_t)c * N_NODES,
                                              dinv + (size_t)c * N_NODES);
    make_dinv_kernel<<<g3N, B, 0, stream>>>(dinv, 3 * N_NODES);

    // parallel scan: counts[3N] -> row_ptr[3N+1] (global CSR offsets)
    scan1_kernel<<<SCAN_G, SCAN_B, 0, stream>>>(fill, row_ptr, blocksum);
    scan2_kernel<<<1, SCAN_B, 0, stream>>>(blocksum);
    scan3_kernel<<<g3N, B, 0, stream>>>(row_ptr, blocksum);

    // scatter into CSR (fill re-zeroed)
    hipMemsetAsync(fill, 0, 3 * (size_t)N_NODES * sizeof(int), stream);
    for (int c = 0; c < 3; c++)
        scatter_kernel<<<gE, B, 0, stream>>>(ei[c], ea[c], dinv + (size_t)c * N_NODES,
                                             row_ptr + (size_t)c * N_NODES,
                                             fill + (size_t)c * N_NODES, csr);

    // layer 1 per channel: matmul -> gather+finalize
    for (int c = 0; c < 3; c++) {
        matmul_in_kernel<<<gN8, B, 0, stream>>>(x[c], W[c], h_tmp);
        gather_finalize_kernel<<<gN8, B, 0, stream>>>(
            row_ptr + (size_t)c * N_NODES, csr,
            h_tmp, dinv + (size_t)c * N_NODES, b[c], att_w,
            emb + (size_t)c * N_NODES * HID_DIM, coef + (size_t)c * N_NODES);
    }

    // attention combine
    combine_kernel<<<gN, B, 0, stream>>>(emb, emb + (size_t)N_NODES * HID_DIM,
                                         emb + 2 * (size_t)N_NODES * HID_DIM,
                                         coef, coef + N_NODES, coef + 2 * N_NODES,
                                         hmix, wout);

    // layer 2: out = sum_c gcn_conv(hmix, ei_c, ea_c, Wo_c, bo_c)
    init_out_kernel<<<gN32, B, 0, stream>>>(bo[0], bo[1], bo[2], out);
    for (int c = 0; c < 3; c++) {
        matmul_hid_kernel<<<gN8, B, 0, stream>>>(hmix, Wo[c], dinv + (size_t)c * N_NODES,
                                                 h2, out);
        gather_add_kernel<<<gN8, B, 0, stream>>>(row_ptr + (size_t)c * N_NODES, csr, h2, out);
    }
}

// Round 4
// 1152.692 us; speedup vs baseline: 3.9237x; 1.1861x over previous
//
#include <hip/hip_runtime.h>

#define N_NODES 100000
#define N_EDGES 1600000
#define IN_DIM  128
#define HID_DIM 32
#define OUT_DIM 32

#define SCAN_B    256
#define SCAN_VT   8
#define SCAN_CHUNK (SCAN_B * SCAN_VT)   // 2048
#define SCAN_N    (3 * N_NODES)          // 300000 (multiple of 8)
#define SCAN_G    ((SCAN_N + SCAN_CHUNK - 1) / SCAN_CHUNK)  // 147

// ---------------- fused histogram + weighted degree, single 64-bit atomic/edge ----
// packed[v] accumulates: count in bits [48..63], sum(ea)*2^32 in bits [0..47].
// ea ~ U[0,1), max count ~100 -> weight sum < 2^38, no overflow into count field.

__global__ void hist_deg_kernel(const int* __restrict__ ei0, const int* __restrict__ ei1,
                                const int* __restrict__ ei2,
                                const float* __restrict__ ea0, const float* __restrict__ ea1,
                                const float* __restrict__ ea2,
                                unsigned long long* __restrict__ packed) {
    int e = blockIdx.x * blockDim.x + threadIdx.x;
    if (e >= 3 * N_EDGES) return;
    int c = (e >= 2 * N_EDGES) ? 2 : ((e >= N_EDGES) ? 1 : 0);
    int le = e - c * N_EDGES;
    const int* ei = (c == 0) ? ei0 : (c == 1) ? ei1 : ei2;
    const float* ea = (c == 0) ? ea0 : (c == 1) ? ea1 : ea2;
    int col = ei[N_EDGES + le];
    unsigned long long w = (unsigned long long)((double)ea[le] * 4294967296.0);
    atomicAdd(&packed[(size_t)c * N_NODES + col], (1ULL << 48) + w);
}

// unpack: dinv = rsqrt(1 + wsum), counts for the scan
__global__ void unpack_kernel(const unsigned long long* __restrict__ packed,
                              float* __restrict__ dinv, int* __restrict__ count) {
    int i = blockIdx.x * blockDim.x + threadIdx.x;
    if (i >= SCAN_N) return;
    unsigned long long v = packed[i];
    count[i] = (int)(v >> 48);
    double deg = 1.0 + (double)(v & ((1ULL << 48) - 1)) * (1.0 / 4294967296.0);
    dinv[i] = (float)rsqrt(deg);
}

// ---------------- parallel 3-phase scan over counts[3N] -> row_ptr[3N+1] --------
// Channel c's CSR base offset (c * N_EDGES) emerges automatically since each
// channel contributes exactly N_EDGES edges.

__global__ void scan1_kernel(const int* __restrict__ counts, int* __restrict__ rp1,
                             int* __restrict__ blocksum) {
    __shared__ int wsum[4];
    int tid = threadIdx.x;
    int base = blockIdx.x * SCAN_CHUNK + tid * SCAN_VT;
    int vals[SCAN_VT];
    int tsum = 0;
    if (base < SCAN_N) {        // SCAN_N multiple of 8 -> all-or-nothing per thread
        int4 v0 = *(const int4*)(counts + base);
        int4 v1 = *(const int4*)(counts + base + 4);
        vals[0] = v0.x; vals[1] = v0.y; vals[2] = v0.z; vals[3] = v0.w;
        vals[4] = v1.x; vals[5] = v1.y; vals[6] = v1.z; vals[7] = v1.w;
#pragma unroll
        for (int k = 0; k < SCAN_VT; k++) tsum += vals[k];
    } else {
#pragma unroll
        for (int k = 0; k < SCAN_VT; k++) vals[k] = 0;
    }
    int lane = tid & 63, wave = tid >> 6;
    int x = tsum;
    for (int d = 1; d < 64; d <<= 1) {
        int t = __shfl_up(x, d, 64);
        if (lane >= d) x += t;
    }
    if (lane == 63) wsum[wave] = x;
    __syncthreads();
    int waveoff = 0;
    for (int w = 0; w < wave; w++) waveoff += wsum[w];
    int run = waveoff + x - tsum;     // exclusive prefix for this thread (block-local)
    if (base < SCAN_N) {
#pragma unroll
        for (int k = 0; k < SCAN_VT; k++) {
            run += vals[k];
            rp1[base + k + 1] = run;  // block-local inclusive
        }
    }
    if (tid == SCAN_B - 1) blocksum[blockIdx.x] = waveoff + x;  // block total
}

__global__ void scan2_kernel(int* __restrict__ blocksum) {   // G <= 256
    __shared__ int wsum[4];
    int tid = threadIdx.x;
    int lane = tid & 63, wave = tid >> 6;
    int v = (tid < SCAN_G) ? blocksum[tid] : 0;
    int x = v;
    for (int d = 1; d < 64; d <<= 1) {
        int t = __shfl_up(x, d, 64);
        if (lane >= d) x += t;
    }
    if (lane == 63) wsum[wave] = x;
    __syncthreads();
    int waveoff = 0;
    for (int w = 0; w < wave; w++) waveoff += wsum[w];
    if (tid < SCAN_G) blocksum[tid] = waveoff + x - v;   // exclusive
}

__global__ void scan3_kernel(int* __restrict__ rp1, const int* __restrict__ blocksum) {
    int i = blockIdx.x * blockDim.x + threadIdx.x;
    if (i < SCAN_N) rp1[i + 1] += blocksum[i / SCAN_CHUNK];
    if (i == 0) rp1[0] = 0;
}

// ---------------- scatter all 3 channels into CSR slots with precomputed norm ----

__global__ void scatter_kernel(const int* __restrict__ ei0, const int* __restrict__ ei1,
                               const int* __restrict__ ei2,
                               const float* __restrict__ ea0, const float* __restrict__ ea1,
                               const float* __restrict__ ea2,
                               const float* __restrict__ dinv,
                               const int* __restrict__ row_ptr, int* __restrict__ fill,
                               int2* __restrict__ csr) {
    int e = blockIdx.x * blockDim.x + threadIdx.x;
    if (e >= 3 * N_EDGES) return;
    int c = (e >= 2 * N_EDGES) ? 2 : ((e >= N_EDGES) ? 1 : 0);
    int le = e - c * N_EDGES;
    const int* ei = (c == 0) ? ei0 : (c == 1) ? ei1 : ei2;
    const float* ea = (c == 0) ? ea0 : (c == 1) ? ea1 : ea2;
    int row = ei[le];
    int col = ei[N_EDGES + le];
    size_t cv = (size_t)c * N_NODES;
    float norm = dinv[cv + row] * ea[le] * dinv[cv + col];
    int slot = row_ptr[cv + col] + atomicAdd(&fill[cv + col], 1);  // global slot
    csr[slot] = make_int2(row, __float_as_int(norm));
}

// ---------------- matmul: x[N,128] @ W[128,32] -> h[N,32] ----------------

__global__ void matmul_in_kernel(const float* __restrict__ x, const float* __restrict__ W,
                                 float* __restrict__ h) {
    __shared__ float Ws[IN_DIM * HID_DIM];   // 16 KB
    for (int i = threadIdx.x; i < IN_DIM * HID_DIM; i += blockDim.x) Ws[i] = W[i];
    __syncthreads();
    int gid = blockIdx.x * blockDim.x + threadIdx.x;
    int v = gid >> 3;
    int t = gid & 7;
    if (v >= N_NODES) return;
    const float* xr = x + (size_t)v * IN_DIM;
    float a0 = 0.f, a1 = 0.f, a2 = 0.f, a3 = 0.f;
#pragma unroll
    for (int j = 0; j < IN_DIM; j += 4) {
        float4 xv = *(const float4*)(xr + j);
        const float* w = &Ws[j * HID_DIM + t];
        a0 += xv.x * w[0];   a1 += xv.x * w[8];   a2 += xv.x * w[16];  a3 += xv.x * w[24];
        a0 += xv.y * w[32];  a1 += xv.y * w[40];  a2 += xv.y * w[48];  a3 += xv.y * w[56];
        a0 += xv.z * w[64];  a1 += xv.z * w[72];  a2 += xv.z * w[80];  a3 += xv.z * w[88];
        a0 += xv.w * w[96];  a1 += xv.w * w[104]; a2 += xv.w * w[112]; a3 += xv.w * w[120];
    }
    float* hr = h + (size_t)v * HID_DIM;
    hr[t] = a0; hr[t + 8] = a1; hr[t + 16] = a2; hr[t + 24] = a3;
}

// ---------------- matmul: hmix[N,32] @ Wo[32,32] -> h2[N,32], + self-loop into out ----

__global__ void matmul_hid_kernel(const float* __restrict__ hin, const float* __restrict__ Wo,
                                  const float* __restrict__ dinv,
                                  float* __restrict__ h2, float* __restrict__ out) {
    __shared__ float Ws[HID_DIM * OUT_DIM];  // 4 KB
    for (int i = threadIdx.x; i < HID_DIM * OUT_DIM; i += blockDim.x) Ws[i] = Wo[i];
    __syncthreads();
    int gid = blockIdx.x * blockDim.x + threadIdx.x;
    int v = gid >> 3;
    int t = gid & 7;
    if (v >= N_NODES) return;
    const float* hr = hin + (size_t)v * HID_DIM;
    float a0 = 0.f, a1 = 0.f, a2 = 0.f, a3 = 0.f;
#pragma unroll
    for (int j = 0; j < HID_DIM; j += 4) {
        float4 hv = *(const float4*)(hr + j);
        const float* w = &Ws[j * OUT_DIM + t];
        a0 += hv.x * w[0];   a1 += hv.x * w[8];   a2 += hv.x * w[16];  a3 += hv.x * w[24];
        a0 += hv.y * w[32];  a1 += hv.y * w[40];  a2 += hv.y * w[48];  a3 += hv.y * w[56];
        a0 += hv.z * w[64];  a1 += hv.z * w[72];  a2 += hv.z * w[80];  a3 += hv.z * w[88];
        a0 += hv.w * w[96];  a1 += hv.w * w[104]; a2 += hv.w * w[112]; a3 += hv.w * w[120];
    }
    float s = dinv[v]; s = s * s;   // self-loop norm
    float* h2r = h2 + (size_t)v * OUT_DIM;
    float* outr = out + (size_t)v * OUT_DIM;
    h2r[t]      = a0;  outr[t]      += s * a0;   // exclusive writer, stream-ordered
    h2r[t + 8]  = a1;  outr[t + 8]  += s * a1;
    h2r[t + 16] = a2;  outr[t + 16] += s * a2;
    h2r[t + 24] = a3;  outr[t + 24] += s * a3;
}

// ---------------- layer-1 gather + finalize ----------------

__global__ void gather_finalize_kernel(const int* __restrict__ row_ptr,
                                       const int2* __restrict__ csr,
                                       const float* __restrict__ h,
                                       const float* __restrict__ dinv,
                                       const float* __restrict__ b,
                                       const float* __restrict__ att_w,
                                       float* __restrict__ emb,
                                       float* __restrict__ coef) {
    int gid = blockIdx.x * blockDim.x + threadIdx.x;
    int v = gid >> 3;
    int t = gid & 7;
    if (v >= N_NODES) return;
    int beg = row_ptr[v], end = row_ptr[v + 1];
    float a0 = 0.f, a1 = 0.f, a2 = 0.f, a3 = 0.f;
    for (int e = beg; e < end; e++) {
        int2 p = csr[e];
        float norm = __int_as_float(p.y);
        float4 hv = *(const float4*)(h + (size_t)p.x * 32 + t * 4);
        a0 += norm * hv.x; a1 += norm * hv.y; a2 += norm * hv.z; a3 += norm * hv.w;
    }
    float s = dinv[v]; s = s * s;
    float4 hv = *(const float4*)(h + (size_t)v * 32 + t * 4);
    float4 bv = *(const float4*)(b + t * 4);
    float e0 = fmaxf(a0 + s * hv.x + bv.x, 0.f);
    float e1 = fmaxf(a1 + s * hv.y + bv.y, 0.f);
    float e2 = fmaxf(a2 + s * hv.z + bv.z, 0.f);
    float e3 = fmaxf(a3 + s * hv.w + bv.w, 0.f);
    float4 ev; ev.x = e0; ev.y = e1; ev.z = e2; ev.w = e3;
    *(float4*)(emb + (size_t)v * 32 + t * 4) = ev;
    float4 wv = *(const float4*)(att_w + t * 4);
    float dot = e0 * wv.x + e1 * wv.y + e2 * wv.z + e3 * wv.w;
    dot += __shfl_xor(dot, 1, 64);
    dot += __shfl_xor(dot, 2, 64);
    dot += __shfl_xor(dot, 4, 64);
    if (t == 0) {
        float lr = (dot > 0.0f) ? dot : 0.01f * dot;
        coef[v] = expf(lr);
    }
}

// ---------------- layer-2 gather: out += aggregated h2 ----------------

__global__ void gather_add_kernel(const int* __restrict__ row_ptr,
                                  const int2* __restrict__ csr,
                                  const float* __restrict__ h2,
                                  float* __restrict__ out) {
    int gid = blockIdx.x * blockDim.x + threadIdx.x;
    int v = gid >> 3;
    int t = gid & 7;
    if (v >= N_NODES) return;
    int beg = row_ptr[v], end = row_ptr[v + 1];
    float a0 = 0.f, a1 = 0.f, a2 = 0.f, a3 = 0.f;
    for (int e = beg; e < end; e++) {
        int2 p = csr[e];
        float norm = __int_as_float(p.y);
        float4 hv = *(const float4*)(h2 + (size_t)p.x * 32 + t * 4);
        a0 += norm * hv.x; a1 += norm * hv.y; a2 += norm * hv.z; a3 += norm * hv.w;
    }
    float* o = out + (size_t)v * 32 + t * 4;
    float4 ov = *(float4*)o;
    ov.x += a0; ov.y += a1; ov.z += a2; ov.w += a3;
    *(float4*)o = ov;
}

// ---------------- attention combine ----------------

__global__ void combine_kernel(const float* __restrict__ emb0, const float* __restrict__ emb1,
                               const float* __restrict__ emb2,
                               const float* __restrict__ coef0, const float* __restrict__ coef1,
                               const float* __restrict__ coef2,
                               float* __restrict__ hmix, float* __restrict__ wout) {
    int v = blockIdx.x * blockDim.x + threadIdx.x;
    if (v >= N_NODES) return;
    float c0 = coef0[v], c1 = coef1[v], c2 = coef2[v];
    float inv = 1.0f / (c0 + c1 + c2);
    float w0 = c0 * inv, w1 = c1 * inv, w2 = c2 * inv;
    wout[v] = w0;
    wout[N_NODES + v] = w1;
    wout[2 * N_NODES + v] = w2;
    const float* e0 = emb0 + (size_t)v * HID_DIM;
    const float* e1 = emb1 + (size_t)v * HID_DIM;
    const float* e2 = emb2 + (size_t)v * HID_DIM;
    float* hm = hmix + (size_t)v * HID_DIM;
#pragma unroll
    for (int k = 0; k < HID_DIM; k += 4) {
        float4 a = *(const float4*)(e0 + k);
        float4 b = *(const float4*)(e1 + k);
        float4 c = *(const float4*)(e2 + k);
        float4 r;
        r.x = w0 * a.x + w1 * b.x + w2 * c.x;
        r.y = w0 * a.y + w1 * b.y + w2 * c.y;
        r.z = w0 * a.z + w1 * b.z + w2 * c.z;
        r.w = w0 * a.w + w1 * b.w + w2 * c.w;
        *(float4*)(hm + k) = r;
    }
}

// ---------------- out init with summed biases ----------------

__global__ void init_out_kernel(const float* __restrict__ bo0, const float* __restrict__ bo1,
                                const float* __restrict__ bo2, float* __restrict__ out) {
    int gid = blockIdx.x * blockDim.x + threadIdx.x;
    if (gid >= N_NODES * OUT_DIM) return;
    int k = gid & 31;
    out[gid] = bo0[k] + bo1[k] + bo2[k];
}

// ---------------- launch ----------------

extern "C" void kernel_launch(void* const* d_in, const int* in_sizes, int n_in,
                              void* d_out, int out_size, void* d_ws, size_t ws_size,
                              hipStream_t stream) {
    const float* x[3];  const int* ei[3];  const float* ea[3];
    const float* W[3];  const float* b[3]; const float* Wo[3]; const float* bo[3];
    for (int c = 0; c < 3; c++) {
        x[c]  = (const float*)d_in[7 * c + 0];
        ei[c] = (const int*)  d_in[7 * c + 1];
        ea[c] = (const float*)d_in[7 * c + 2];
        W[c]  = (const float*)d_in[7 * c + 3];
        b[c]  = (const float*)d_in[7 * c + 4];
        Wo[c] = (const float*)d_in[7 * c + 5];
        bo[c] = (const float*)d_in[7 * c + 6];
    }
    const float* att_w = (const float*)d_in[21];
    float* out = (float*)d_out;                 // [N*32] then 3x [N] weights
    float* wout = out + (size_t)N_NODES * OUT_DIM;

    // workspace layout (4-byte units)
    float* ws = (float*)d_ws;
    float* dinv     = ws;                                        // 3N
    int*   row_ptr  = (int*)(dinv + 3 * (size_t)N_NODES);        // 3N+4 (entry [3N] used)
    int*   fill     = row_ptr + 3 * N_NODES + 4;                 // 3N (counts, then fill)
    int*   blocksum = fill + 3 * (size_t)N_NODES;                // 160
    int2*  csr      = (int2*)(blocksum + 160);                   // 3E pairs, global slots
    float* emb      = (float*)(csr + 3 * (size_t)N_EDGES);       // 3*N*32
    float* coef     = emb + 3 * (size_t)N_NODES * HID_DIM;       // 3N
    float* h_tmp    = coef + 3 * (size_t)N_NODES;                // N*32 (reused as h2)
    float* hmix     = h_tmp + (size_t)N_NODES * HID_DIM;         // N*32
    float* h2       = h_tmp;                                     // alias: dead after layer 1
    // packed hist/deg accumulator aliases h_tmp+hmix region (dead until layer 1);
    // offset from ws start is even -> 8B aligned
    unsigned long long* packed = (unsigned long long*)h_tmp;     // 3N u64 = 2.4 MB < 25.6 MB

    const int B = 256;
    const int gN   = (N_NODES + B - 1) / B;
    const int g3N  = (3 * N_NODES + B - 1) / B;
    const int g3E  = (3 * N_EDGES + B - 1) / B;
    const int gN8  = (N_NODES * 8 + B - 1) / B;
    const int gN32 = (N_NODES * 32 + B - 1) / B;

    // fused histogram + weighted degree: one 64-bit atomic per edge
    hipMemsetAsync(packed, 0, 3 * (size_t)N_NODES * sizeof(unsigned long long), stream);
    hist_deg_kernel<<<g3E, B, 0, stream>>>(ei[0], ei[1], ei[2], ea[0], ea[1], ea[2], packed);
    unpack_kernel<<<g3N, B, 0, stream>>>(packed, dinv, fill);

    // parallel scan: counts[3N] -> row_ptr[3N+1] (global CSR offsets)
    scan1_kernel<<<SCAN_G, SCAN_B, 0, stream>>>(fill, row_ptr, blocksum);
    scan2_kernel<<<1, SCAN_B, 0, stream>>>(blocksum);
    scan3_kernel<<<g3N, B, 0, stream>>>(row_ptr, blocksum);

    // scatter into CSR (fill re-zeroed)
    hipMemsetAsync(fill, 0, 3 * (size_t)N_NODES * sizeof(int), stream);
    scatter_kernel<<<g3E, B, 0, stream>>>(ei[0], ei[1], ei[2], ea[0], ea[1], ea[2],
                                          dinv, row_ptr, fill, csr);

    // layer 1 per channel: matmul -> gather+finalize
    for (int c = 0; c < 3; c++) {
        matmul_in_kernel<<<gN8, B, 0, stream>>>(x[c], W[c], h_tmp);
        gather_finalize_kernel<<<gN8, B, 0, stream>>>(
            row_ptr + (size_t)c * N_NODES, csr,
            h_tmp, dinv + (size_t)c * N_NODES, b[c], att_w,
            emb + (size_t)c * N_NODES * HID_DIM, coef + (size_t)c * N_NODES);
    }

    // attention combine
    combine_kernel<<<gN, B, 0, stream>>>(emb, emb + (size_t)N_NODES * HID_DIM,
                                         emb + 2 * (size_t)N_NODES * HID_DIM,
                                         coef, coef + N_NODES, coef + 2 * N_NODES,
                                         hmix, wout);

    // layer 2: out = sum_c gcn_conv(hmix, ei_c, ea_c, Wo_c, bo_c)
    init_out_kernel<<<gN32, B, 0, stream>>>(bo[0], bo[1], bo[2], out);
    for (int c = 0; c < 3; c++) {
        matmul_hid_kernel<<<gN8, B, 0, stream>>>(hmix, Wo[c], dinv + (size_t)c * N_NODES,
                                                 h2, out);
        gather_add_kernel<<<gN8, B, 0, stream>>>(row_ptr + (size_t)c * N_NODES, csr, h2, out);
    }
}